// Round 1
// baseline (553.939 us; speedup 1.0000x reference)
//
#include <hip/hip_runtime.h>
#include <hip/hip_bf16.h>
#include <stdint.h>

// Problem constants
#define Bn 2
#define Ln 2048
#define HIDn 1024
#define NHn 16
#define En 128
#define HSn 64

typedef unsigned short u16;
typedef short s16x8 __attribute__((ext_vector_type(8)));
typedef float f32x4 __attribute__((ext_vector_type(4)));

__device__ __forceinline__ u16 f2bf(float f) {
  union { float f; uint32_t u; } v; v.f = f;
  uint32_t r = (v.u + 0x7fffu + ((v.u >> 16) & 1u)) >> 16;
  return (u16)r;
}
__device__ __forceinline__ float bf2f(u16 b) {
  union { uint32_t u; float f; } v; v.u = ((uint32_t)b) << 16;
  return v.f;
}
// async global->LDS, 16B per lane; lds dest = wave-uniform base + lane*16
__device__ __forceinline__ void async16(const void* g, void* l) {
  __builtin_amdgcn_global_load_lds((const __attribute__((address_space(1))) void*)g,
                                   (__attribute__((address_space(3))) void*)l, 16, 0, 0);
}

// ---------------- cast fp32 -> bf16 ----------------
__global__ void castbf(const float* __restrict__ in, u16* __restrict__ out, int n) {
  int i = (blockIdx.x * blockDim.x + threadIdx.x) * 4;
  if (i >= n) return;
  float4 v = *(const float4*)(in + i);
  u16 o[4] = {f2bf(v.x), f2bf(v.y), f2bf(v.z), f2bf(v.w)};
  *(uint64_t*)(out + i) = *(uint64_t*)o;
}

// ---------------- gate weight pre-sum ----------------
__global__ void wgprep(const float* __restrict__ Wg, float* __restrict__ wgu,
                       float* __restrict__ wgr) {
  int e = threadIdx.x;  // 128 threads
  wgu[e] = Wg[0 * 128 + e] + Wg[1 * 128 + e] + Wg[2 * 128 + e] + Wg[3 * 128 + e];
  wgr[e] = Wg[4 * 128 + e] + Wg[5 * 128 + e] + Wg[6 * 128 + e] + Wg[7 * 128 + e];
}

// ---------------- fused QKV GEMM (bf16 MFMA, 128x128 tile, BK=32) ----------------
// C[row, col] = A[row,:] . W[col,:]
// bx <  16 -> q (+bq), plain (B,NH,L,E)
// bx <  32 -> k, (B,NH,L,E) with e-granule XOR-swizzle by (l&15)
// bx >= 32 -> v (+bv), TRANSPOSED (B,NH,HS,L) with l-granule XOR-swizzle by (hs&7)
// Epilogue goes through LDS so all global stores are 16B, full-line coalesced.
__global__ __launch_bounds__(256) void qkv_gemm(
    const u16* __restrict__ A, const u16* __restrict__ W,
    const float* __restrict__ bq, const float* __restrict__ bv,
    u16* __restrict__ qb, u16* __restrict__ kb, u16* __restrict__ vt) {
  __shared__ union {
    struct { u16 a[128 * 32]; u16 b[128 * 32]; } st;  // 16KB staging
    u16 cq[64][140];    // q/k epilogue: [l_local][e], pad->stride 140
    u16 cv[128][72];    // v  epilogue: [c_local][l_local], pad->stride 72
  } lds;
  const int tid = threadIdx.x, lane = tid & 63, w = tid >> 6;
  const int quad = lane >> 4, ln = lane & 15;
  const int bx = blockIdx.x, by = blockIdx.y;
  const int m0 = (w >> 1) * 64, n0 = (w & 1) * 64;
  f32x4 acc[4][4];
  for (int i = 0; i < 4; ++i)
    for (int j = 0; j < 4; ++j) acc[i][j] = (f32x4)0.0f;

  for (int k0 = 0; k0 < 1024; k0 += 32) {
    __syncthreads();
    for (int cc = 0; cc < 2; ++cc) {
      int c = w * 2 + cc;
      int row = c * 16 + (lane >> 2);
      int ke = (lane & 3) * 8;
      async16(A + (size_t)(by * 128 + row) * 1024 + k0 + ke, lds.st.a + c * 512);
      async16(W + (size_t)(bx * 128 + row) * 1024 + k0 + ke, lds.st.b + c * 512);
    }
    __syncthreads();
    s16x8 a[4], bf[4];
    for (int i = 0; i < 4; ++i)
      a[i] = *(const s16x8*)&lds.st.a[(m0 + i * 16 + ln) * 32 + quad * 8];
    for (int j = 0; j < 4; ++j)
      bf[j] = *(const s16x8*)&lds.st.b[(n0 + j * 16 + ln) * 32 + quad * 8];
    for (int i = 0; i < 4; ++i)
      for (int j = 0; j < 4; ++j)
        acc[i][j] = __builtin_amdgcn_mfma_f32_16x16x32_bf16(a[i], bf[j], acc[i][j], 0, 0, 0);
  }

  // per-lane bias for this wave's 4 column groups
  float bias[4];
#pragma unroll
  for (int j = 0; j < 4; ++j) {
    int col = bx * 128 + n0 + j * 16 + ln;
    bias[j] = (bx < 16) ? bq[col] : (bx >= 32 ? bv[col - 4096] : 0.0f);
  }

  if (bx < 32) {
    // ---- q/k epilogue: stage [l_local 0..63][e 0..127], store 64 rows x 16 segs
    for (int half = 0; half < 2; ++half) {
      __syncthreads();
      if ((w >> 1) == half) {
#pragma unroll
        for (int i = 0; i < 4; ++i)
#pragma unroll
          for (int j = 0; j < 4; ++j)
#pragma unroll
            for (int r = 0; r < 4; ++r)
              lds.cq[i * 16 + quad * 4 + r][n0 + j * 16 + ln] = f2bf(acc[i][j][r] + bias[j]);
      }
      __syncthreads();
#pragma unroll
      for (int it = 0; it < 4; ++it) {
        int slot = it * 256 + tid;        // 64 rows x 16 segs = 1024 slots
        int row = slot >> 4, seg = slot & 15;
        int rowg = by * 128 + half * 64 + row;
        int b = rowg >> 11, l = rowg & 2047;
        uint4 d = *(const uint4*)&lds.cq[row][seg * 8];
        if (bx < 16) {
          *(uint4*)(qb + ((size_t)(b * 16 + bx) * 2048 + l) * 128 + seg * 8) = d;
        } else {
          int sg = (seg ^ (l & 15)) & 15;
          *(uint4*)(kb + ((size_t)(b * 16 + (bx - 16)) * 2048 + l) * 128 + sg * 8) = d;
        }
      }
    }
  } else {
    // ---- v epilogue: stage transposed [c_local 0..127][l_local 0..63]
    for (int half = 0; half < 2; ++half) {
      __syncthreads();
      if ((w >> 1) == half) {
#pragma unroll
        for (int i = 0; i < 4; ++i)
#pragma unroll
          for (int j = 0; j < 4; ++j)
#pragma unroll
            for (int r = 0; r < 4; ++r)
              lds.cv[n0 + j * 16 + ln][i * 16 + quad * 4 + r] = f2bf(acc[i][j][r] + bias[j]);
      }
      __syncthreads();
      int rowg = by * 128 + half * 64;  // 64-aligned, same b for all 64 rows
      int b = rowg >> 11, lbase = rowg & 2047;
#pragma unroll
      for (int it = 0; it < 4; ++it) {
        int slot = it * 256 + tid;          // 128 rows x 8 segs
        int row = slot >> 3, seg = slot & 7;
        int c2 = (bx - 32) * 128 + row;
        int h = c2 >> 6, hs = c2 & 63;
        int sg = seg ^ (hs & 7);
        uint4 d = *(const uint4*)&lds.cv[row][seg * 8];
        *(uint4*)(vt + ((size_t)(b * 16 + h) * 64 + hs) * 2048 + lbase + sg * 8) = d;
      }
    }
  }
}

// ---------------- gate kernel (plain q layout) ----------------
__global__ void gate_kernel(const u16* __restrict__ qb, const float* __restrict__ wgu,
                            const float* __restrict__ wgr, const float* __restrict__ bg,
                            const float* __restrict__ eco, float* __restrict__ gate) {
  int t = blockIdx.x * 256 + threadIdx.x;  // 65536 rows = (b,h,l)
  int h = (t >> 11) & 15;
  const u16* q = qb + (size_t)t * 128;
  float u = bg[0] + bg[1] + bg[2] + bg[3];
  float rr = bg[4] + bg[5] + bg[6] + bg[7];
  for (int e = 0; e < 128; e += 8) {
    uint4 d = *(const uint4*)(q + e);
    const u16* p = (const u16*)&d;
#pragma unroll
    for (int jj = 0; jj < 8; ++jj) {
      float f = bf2f(p[jj]);
      u += f * wgu[e + jj];
      rr += f * wgr[e + jj];
    }
  }
  float gu = 1.0f / (1.0f + __expf(-u));
  float gr = 1.0f / (1.0f + __expf(-rr));
  gate[t] = gu * (gr * eco[h] - 1.0f) + 2.0f;
}

// ---------------- flash attention (single-barrier double-buffered pipeline) ----------------
// grid: (L/128 * 2, NH): bx = qt*2 + b (rel_pos twins dispatch-adjacent -> L3 hit)
// block 512 = 8 waves, wave w owns q rows [w*16, w*16+16) of a 128-row q tile.
// Per tile: ONE barrier. Staging for tile t+1 (global_load_lds into buf^1) and the
// rel_pos register prefetch for t+1 are issued right after the barrier, so the
// compiler's vmcnt(0)-before-barrier drain lands a full tile of compute later.
__global__ __launch_bounds__(512, 4) void attn_kernel(
    const u16* __restrict__ qb, const u16* __restrict__ kb, const u16* __restrict__ vt,
    const float* __restrict__ mask, const float* __restrict__ relpos,
    const float* __restrict__ gate, float* __restrict__ out) {
  __shared__ u16 sK[2][64 * 128];   // 2 x 16KB  [kr][e-granules swizzled by kr&15]
  __shared__ u16 sVt[2][64 * 64];   // 2 x 8KB   [hs][k-granules swizzled by hs&7]
  __shared__ u16 sP[8][16 * 72];    // per-wave P [m][k], stride 72 (18KB)

  const int tid = threadIdx.x, lane = tid & 63, w = tid >> 6;
  const int quad = lane >> 4, ln = lane & 15;
  const int bx = blockIdx.x, h = blockIdx.y;
  const int qt = bx >> 1, b = bx & 1;
  const int q0 = qt * 128;
  const u16* qptr = qb + (size_t)(b * NHn + h) * Ln * En;
  const u16* kptr = kb + (size_t)(b * NHn + h) * Ln * En;
  const u16* vptr = vt + (size_t)(b * NHn + h) * HSn * Ln;
  const float* rp = relpos + (size_t)h * Ln * Ln + (size_t)q0 * Ln;
  const float* mk = mask + (size_t)b * Ln;
  const float* gt = gate + (size_t)(b * NHn + h) * Ln;

  // Q fragments straight to registers (plain layout, no LDS)
  s16x8 aq[4];
  {
    const u16* qrow = qptr + (size_t)(q0 + w * 16 + ln) * En;
#pragma unroll
    for (int es = 0; es < 4; ++es)
      aq[es] = *(const s16x8*)(qrow + (es * 4 + quad) * 8);
  }
  float gv[4];
#pragma unroll
  for (int r = 0; r < 4; ++r) gv[r] = gt[q0 + w * 16 + quad * 4 + r];

  float l_part[4] = {0.0f, 0.0f, 0.0f, 0.0f};
  f32x4 O[4];
#pragma unroll
  for (int j = 0; j < 4; ++j) O[j] = (f32x4)0.0f;

  // stage K (64x128, 16KB) + V^T (64x64, 8KB) for tile kt into buffer buf.
  // Rows are verbatim copies - global layout is already swizzled/transposed.
  auto stage = [&](int buf, int kt) {
    const int kbase = kt * 64;
#pragma unroll
    for (int cc = 0; cc < 2; ++cc) {
      int c = w * 2 + cc;  // 0..15, each = 1KB = 4 K-rows
      async16(kptr + (size_t)(kbase + c * 4 + (lane >> 4)) * En + (lane & 15) * 8,
              &sK[buf][c * 512]);
    }
    // c = w: 1KB = 8 V-rows
    async16(vptr + (size_t)(w * 8 + (lane >> 3)) * Ln + kbase + (lane & 7) * 8,
            &sVt[buf][w * 512]);
  };
  // rel_pos register prefetch for tile kt (this wave's 16 q rows x 64 k cols)
  auto ldrp = [&](int kt, float (&rv)[4][4]) {
    const float* rpr = rp + (size_t)(w * 16 + quad * 4) * Ln + kt * 64 + ln;
#pragma unroll
    for (int r = 0; r < 4; ++r)
#pragma unroll
      for (int j = 0; j < 4; ++j) rv[j][r] = rpr[(size_t)r * Ln + j * 16];
  };

  // prologue: tile 0 staging + rel_pos prefetch
  stage(0, 0);
  float rpc[4][4];
  ldrp(0, rpc);

  for (int kt = 0; kt < Ln / 64; ++kt) {
    const int cur = kt & 1;
    __syncthreads();  // vmcnt(0) drain: staging+prefetch issued a full tile ago
    if (kt + 1 < Ln / 64) stage(cur ^ 1, kt + 1);
    float mv[4];
#pragma unroll
    for (int j = 0; j < 4; ++j) mv[j] = mk[kt * 64 + j * 16 + ln];
    float rpn[4][4];
    if (kt + 1 < Ln / 64) ldrp(kt + 1, rpn);

    // S = Q.K^T  (16 q-rows x 64 k-cols per wave)
    f32x4 S[4];
#pragma unroll
    for (int j = 0; j < 4; ++j) S[j] = (f32x4)0.0f;
#pragma unroll
    for (int es = 0; es < 4; ++es) {
#pragma unroll
      for (int j = 0; j < 4; ++j) {
        s16x8 bk = *(const s16x8*)&sK[cur][(j * 16 + ln) * 128 + (((es * 4 + quad) ^ ln) & 15) * 8];
        S[j] = __builtin_amdgcn_mfma_f32_16x16x32_bf16(aq[es], bk, S[j], 0, 0, 0);
      }
    }
    // combine + exp (no max subtraction: scores bounded ~|12|, fp32 exp safe)
#pragma unroll
    for (int j = 0; j < 4; ++j) {
#pragma unroll
      for (int r = 0; r < 4; ++r) {
        float p = __expf(S[j][r] * 0.125f + mv[j] + gv[r] * rpc[j][r]);
        l_part[r] += p;
        sP[w][(quad * 4 + r) * 72 + j * 16 + ln] = f2bf(p);
      }
    }
    // O += P.V  (per-wave sP: in-order LDS pipe, no barrier needed)
#pragma unroll
    for (int ks = 0; ks < 2; ++ks) {
      s16x8 ap = *(const s16x8*)&sP[w][ln * 72 + ks * 32 + quad * 8];
#pragma unroll
      for (int j = 0; j < 4; ++j) {
        s16x8 bv_ = *(const s16x8*)&sVt[cur][(j * 16 + ln) * 64 + (((ks * 4 + quad) ^ (ln & 7)) & 7) * 8];
        O[j] = __builtin_amdgcn_mfma_f32_16x16x32_bf16(ap, bv_, O[j], 0, 0, 0);
      }
    }
    // rotate rel_pos prefetch
    if (kt + 1 < Ln / 64) {
#pragma unroll
      for (int j = 0; j < 4; ++j)
#pragma unroll
        for (int r = 0; r < 4; ++r) rpc[j][r] = rpn[j][r];
    }
  }

  // final l reduction over the 16 ln-lanes (once, not per tile)
#pragma unroll
  for (int r = 0; r < 4; ++r) {
    float l = l_part[r];
    l += __shfl_xor(l, 1, 64);
    l += __shfl_xor(l, 2, 64);
    l += __shfl_xor(l, 4, 64);
    l += __shfl_xor(l, 8, 64);
    float inv = 1.0f / l;
    int qrow = q0 + w * 16 + quad * 4 + r;
    float* op = out + ((size_t)b * Ln + qrow) * HIDn + h * 64;
#pragma unroll
    for (int j = 0; j < 4; ++j) op[j * 16 + ln] = O[j][r] * inv;
  }
}

extern "C" void kernel_launch(void* const* d_in, const int* in_sizes, int n_in,
                              void* d_out, int out_size, void* d_ws, size_t ws_size,
                              hipStream_t stream) {
  const float* hs = (const float*)d_in[0];
  const float* mask = (const float*)d_in[1];
  const float* relpos = (const float*)d_in[2];
  const float* Wq = (const float*)d_in[3];
  const float* bq = (const float*)d_in[4];
  const float* Wk = (const float*)d_in[5];
  const float* Wv = (const float*)d_in[6];
  const float* bv = (const float*)d_in[7];
  const float* Wg = (const float*)d_in[8];
  const float* bg = (const float*)d_in[9];
  const float* eco = (const float*)d_in[10];
  float* out = (float*)d_out;

  char* ws = (char*)d_ws;
  u16* hsb = (u16*)ws;                           // 8MB
  u16* wb = (u16*)(ws + (8ull << 20));           // 10MB
  u16* qb = (u16*)(ws + (18ull << 20));          // 16MB
  u16* kb = (u16*)(ws + (34ull << 20));          // 16MB
  u16* vt = (u16*)(ws + (50ull << 20));          // 8MB
  float* gate = (float*)(ws + (58ull << 20));    // 256KB
  float* wgu = (float*)(ws + (58ull << 20) + (1ull << 19));
  float* wgr = wgu + 128;

  castbf<<<4096, 256, 0, stream>>>(hs, hsb, 4096 * 1024);
  castbf<<<2048, 256, 0, stream>>>(Wq, wb, 2048 * 1024);
  castbf<<<2048, 256, 0, stream>>>(Wk, wb + 2048 * 1024, 2048 * 1024);
  castbf<<<1024, 256, 0, stream>>>(Wv, wb + 4096 * 1024, 1024 * 1024);
  wgprep<<<1, 128, 0, stream>>>(Wg, wgu, wgr);
  qkv_gemm<<<dim3(40, 32), 256, 0, stream>>>(hsb, wb, bq, bv, qb, kb, vt);
  gate_kernel<<<256, 256, 0, stream>>>(qb, wgu, wgr, bg, eco, gate);
  attn_kernel<<<dim3(32, 16), 512, 0, stream>>>(qb, kb, vt, mask, relpos, gate, out);
}

// Round 3
// 551.013 us; speedup vs baseline: 1.0053x; 1.0053x over previous
//
#include <hip/hip_runtime.h>
#include <hip/hip_bf16.h>
#include <stdint.h>

// Problem constants
#define Bn 2
#define Ln 2048
#define HIDn 1024
#define NHn 16
#define En 128
#define HSn 64

typedef unsigned short u16;
typedef short s16x8 __attribute__((ext_vector_type(8)));
typedef float f32x4 __attribute__((ext_vector_type(4)));
typedef float f32x16 __attribute__((ext_vector_type(16)));

__device__ __forceinline__ u16 f2bf(float f) {
  union { float f; uint32_t u; } v; v.f = f;
  uint32_t r = (v.u + 0x7fffu + ((v.u >> 16) & 1u)) >> 16;
  return (u16)r;
}
__device__ __forceinline__ float bf2f(u16 b) {
  union { uint32_t u; float f; } v; v.u = ((uint32_t)b) << 16;
  return v.f;
}
// async global->LDS, 16B per lane; lds dest = wave-uniform base + lane*16
__device__ __forceinline__ void async16(const void* g, void* l) {
  __builtin_amdgcn_global_load_lds((const __attribute__((address_space(1))) void*)g,
                                   (__attribute__((address_space(3))) void*)l, 16, 0, 0);
}

// ---------------- cast fp32 -> bf16 ----------------
__global__ void castbf(const float* __restrict__ in, u16* __restrict__ out, int n) {
  int i = (blockIdx.x * blockDim.x + threadIdx.x) * 4;
  if (i >= n) return;
  float4 v = *(const float4*)(in + i);
  u16 o[4] = {f2bf(v.x), f2bf(v.y), f2bf(v.z), f2bf(v.w)};
  *(uint64_t*)(out + i) = *(uint64_t*)o;
}

// ---------------- gate weight pre-sum ----------------
__global__ void wgprep(const float* __restrict__ Wg, float* __restrict__ wgu,
                       float* __restrict__ wgr) {
  int e = threadIdx.x;  // 128 threads
  wgu[e] = Wg[0 * 128 + e] + Wg[1 * 128 + e] + Wg[2 * 128 + e] + Wg[3 * 128 + e];
  wgr[e] = Wg[4 * 128 + e] + Wg[5 * 128 + e] + Wg[6 * 128 + e] + Wg[7 * 128 + e];
}

// ---------------- fused QKV GEMM (bf16 MFMA, 128x128 tile, BK=32) ----------------
// C[row, col] = A[row,:] . W[col,:]
// bx <  16 -> q (+bq), plain (B,NH,L,E)
// bx <  32 -> k, (B,NH,L,E) with e-granule XOR-swizzle by (l&15)
// bx >= 32 -> v (+bv), TRANSPOSED (B,NH,HS,L) with l-granule XOR-swizzle by (hs&7)
__global__ __launch_bounds__(256) void qkv_gemm(
    const u16* __restrict__ A, const u16* __restrict__ W,
    const float* __restrict__ bq, const float* __restrict__ bv,
    u16* __restrict__ qb, u16* __restrict__ kb, u16* __restrict__ vt) {
  __shared__ union {
    struct { u16 a[128 * 32]; u16 b[128 * 32]; } st;  // 16KB staging
    u16 cq[64][140];    // q/k epilogue: [l_local][e], pad->stride 140
    u16 cv[128][72];    // v  epilogue: [c_local][l_local], pad->stride 72
  } lds;
  const int tid = threadIdx.x, lane = tid & 63, w = tid >> 6;
  const int quad = lane >> 4, ln = lane & 15;
  const int bx = blockIdx.x, by = blockIdx.y;
  const int m0 = (w >> 1) * 64, n0 = (w & 1) * 64;
  f32x4 acc[4][4];
  for (int i = 0; i < 4; ++i)
    for (int j = 0; j < 4; ++j) acc[i][j] = (f32x4)0.0f;

  for (int k0 = 0; k0 < 1024; k0 += 32) {
    __syncthreads();
    for (int cc = 0; cc < 2; ++cc) {
      int c = w * 2 + cc;
      int row = c * 16 + (lane >> 2);
      int ke = (lane & 3) * 8;
      async16(A + (size_t)(by * 128 + row) * 1024 + k0 + ke, lds.st.a + c * 512);
      async16(W + (size_t)(bx * 128 + row) * 1024 + k0 + ke, lds.st.b + c * 512);
    }
    __syncthreads();
    s16x8 a[4], bf[4];
    for (int i = 0; i < 4; ++i)
      a[i] = *(const s16x8*)&lds.st.a[(m0 + i * 16 + ln) * 32 + quad * 8];
    for (int j = 0; j < 4; ++j)
      bf[j] = *(const s16x8*)&lds.st.b[(n0 + j * 16 + ln) * 32 + quad * 8];
    for (int i = 0; i < 4; ++i)
      for (int j = 0; j < 4; ++j)
        acc[i][j] = __builtin_amdgcn_mfma_f32_16x16x32_bf16(a[i], bf[j], acc[i][j], 0, 0, 0);
  }

  // per-lane bias for this wave's 4 column groups
  float bias[4];
#pragma unroll
  for (int j = 0; j < 4; ++j) {
    int col = bx * 128 + n0 + j * 16 + ln;
    bias[j] = (bx < 16) ? bq[col] : (bx >= 32 ? bv[col - 4096] : 0.0f);
  }

  if (bx < 32) {
    // ---- q/k epilogue: stage [l_local 0..63][e 0..127], store 64 rows x 16 segs
    for (int half = 0; half < 2; ++half) {
      __syncthreads();
      if ((w >> 1) == half) {
#pragma unroll
        for (int i = 0; i < 4; ++i)
#pragma unroll
          for (int j = 0; j < 4; ++j)
#pragma unroll
            for (int r = 0; r < 4; ++r)
              lds.cq[i * 16 + quad * 4 + r][n0 + j * 16 + ln] = f2bf(acc[i][j][r] + bias[j]);
      }
      __syncthreads();
#pragma unroll
      for (int it = 0; it < 4; ++it) {
        int slot = it * 256 + tid;        // 64 rows x 16 segs = 1024 slots
        int row = slot >> 4, seg = slot & 15;
        int rowg = by * 128 + half * 64 + row;
        int b = rowg >> 11, l = rowg & 2047;
        uint4 d = *(const uint4*)&lds.cq[row][seg * 8];
        if (bx < 16) {
          *(uint4*)(qb + ((size_t)(b * 16 + bx) * 2048 + l) * 128 + seg * 8) = d;
        } else {
          int sg = (seg ^ (l & 15)) & 15;
          *(uint4*)(kb + ((size_t)(b * 16 + (bx - 16)) * 2048 + l) * 128 + sg * 8) = d;
        }
      }
    }
  } else {
    // ---- v epilogue: stage transposed [c_local 0..127][l_local 0..63]
    for (int half = 0; half < 2; ++half) {
      __syncthreads();
      if ((w >> 1) == half) {
#pragma unroll
        for (int i = 0; i < 4; ++i)
#pragma unroll
          for (int j = 0; j < 4; ++j)
#pragma unroll
            for (int r = 0; r < 4; ++r)
              lds.cv[n0 + j * 16 + ln][i * 16 + quad * 4 + r] = f2bf(acc[i][j][r] + bias[j]);
      }
      __syncthreads();
      int rowg = by * 128 + half * 64;  // 64-aligned, same b for all 64 rows
      int b = rowg >> 11, lbase = rowg & 2047;
#pragma unroll
      for (int it = 0; it < 4; ++it) {
        int slot = it * 256 + tid;          // 128 rows x 8 segs
        int row = slot >> 3, seg = slot & 7;
        int c2 = (bx - 32) * 128 + row;
        int h = c2 >> 6, hs = c2 & 63;
        int sg = seg ^ (hs & 7);
        uint4 d = *(const uint4*)&lds.cv[row][seg * 8];
        *(uint4*)(vt + ((size_t)(b * 16 + h) * 64 + hs) * 2048 + lbase + sg * 8) = d;
      }
    }
  }
}

// ---------------- gate kernel (plain q layout) ----------------
__global__ void gate_kernel(const u16* __restrict__ qb, const float* __restrict__ wgu,
                            const float* __restrict__ wgr, const float* __restrict__ bg,
                            const float* __restrict__ eco, float* __restrict__ gate) {
  int t = blockIdx.x * 256 + threadIdx.x;  // 65536 rows = (b,h,l)
  int h = (t >> 11) & 15;
  const u16* q = qb + (size_t)t * 128;
  float u = bg[0] + bg[1] + bg[2] + bg[3];
  float rr = bg[4] + bg[5] + bg[6] + bg[7];
  for (int e = 0; e < 128; e += 8) {
    uint4 d = *(const uint4*)(q + e);
    const u16* p = (const u16*)&d;
#pragma unroll
    for (int jj = 0; jj < 8; ++jj) {
      float f = bf2f(p[jj]);
      u += f * wgu[e + jj];
      rr += f * wgr[e + jj];
    }
  }
  float gu = 1.0f / (1.0f + __expf(-u));
  float gr = 1.0f / (1.0f + __expf(-rr));
  gate[t] = gu * (gr * eco[h] - 1.0f) + 2.0f;
}

// ---------------- flash attention v3 (fixed) ----------------
// 32x32x16 MFMA, swapped QK^T (S^T: q = lane&31 -> gate/l/P all lane-local),
// in-register P via v_cvt_pk_bf16_f32 + v_permlane32_swap_b32 (no sP LDS),
// rel_pos reg-staged (coalesced float4) -> XOR-swizzled f32 LDS tile.
// block = 256 thr = 4 waves, each wave 32 q-rows -> q-tile 128.
// grid (L/128*2, NH), bx = qt*2 + b (rel_pos b-twins adjacent -> L3 dedup).
// LDS = 32K(sK db) + 16K(sVt db) + 32K(sRP) = 80KB exactly -> 2 blocks/CU.
// Fixes vs v3: exp reads sRP row (w*32+q5), not q5 (waves 1-3 read wrong rel_pos);
//              epilogue 1/l via __shfl (old sL aliased sRP rows 0-1 -> race).
__global__ __launch_bounds__(256, 2) void attn_kernel(
    const u16* __restrict__ qb, const u16* __restrict__ kbp, const u16* __restrict__ vt,
    const float* __restrict__ mask, const float* __restrict__ relpos,
    const float* __restrict__ gate, float* __restrict__ out) {
  __shared__ u16 sK[2][64 * 128];    // [kr][e-granule ^ (kr&15)]
  __shared__ u16 sVt[2][64 * 64];    // [hs][k-granule ^ (hs&7)]
  __shared__ float sRP[128 * 64];    // [q][k-granule(4f) ^ (q&15)]

  const int tid = threadIdx.x, lane = tid & 63, w = tid >> 6;
  const int q5 = lane & 31, hi = lane >> 5;
  const int bx = blockIdx.x, h = blockIdx.y;
  const int qt = bx >> 1, b = bx & 1;
  const int q0 = qt * 128;
  const u16* qptr = qb + (size_t)(b * NHn + h) * Ln * En;
  const u16* kptr = kbp + (size_t)(b * NHn + h) * Ln * En;
  const u16* vptr = vt + (size_t)(b * NHn + h) * HSn * Ln;
  const float* rpb = relpos + (size_t)h * Ln * Ln + (size_t)q0 * Ln;
  const float* mk = mask + (size_t)b * Ln;
  const float* gt = gate + (size_t)(b * NHn + h) * Ln;

  // Q as B-operand frags: lane holds Q[q = q0+w*32+q5][e = es*16 + hi*8 + t]
  s16x8 aq[8];
  {
    const u16* qrow = qptr + (size_t)(q0 + w * 32 + q5) * En;
#pragma unroll
    for (int es = 0; es < 8; ++es)
      aq[es] = *(const s16x8*)(qrow + es * 16 + hi * 8);
  }
  const float gv = gt[q0 + w * 32 + q5];  // one gate per lane (own q-row)

  float l_part = 0.0f;
  f32x16 O0 = (f32x16)0.0f, O1 = (f32x16)0.0f;

  // stage K (64x128) + V^T (64x64) tile kt -> buf (verbatim; global pre-swizzled)
  auto stage = [&](int buf, int kt) {
    const int kbase = kt * 64;
#pragma unroll
    for (int cc = 0; cc < 4; ++cc) {
      int c = w * 4 + cc;  // 16 chunks of 1KB = 4 K-rows
      async16(kptr + (size_t)(kbase + c * 4 + (lane >> 4)) * En + (lane & 15) * 8,
              &sK[buf][c * 512]);
    }
#pragma unroll
    for (int cc = 0; cc < 2; ++cc) {
      int c = w * 2 + cc;  // 8 chunks of 1KB = 8 V-rows
      async16(vptr + (size_t)(c * 8 + (lane >> 3)) * Ln + kbase + (lane & 7) * 8,
              &sVt[buf][c * 512]);
    }
  };
  // coalesced rel_pos tile load: thread covers 8 float4 granules
  auto rpload = [&](int kt, float4 (&rg)[8]) {
#pragma unroll
    for (int i = 0; i < 8; ++i) {
      int s = i * 256 + tid;           // 128 rows x 16 granules
      int qq = s >> 4, gc = s & 15;
      rg[i] = *(const float4*)(rpb + (size_t)qq * Ln + kt * 64 + gc * 4);
    }
  };
  auto rpwrite = [&](const float4 (&rg)[8]) {
#pragma unroll
    for (int i = 0; i < 8; ++i) {
      int s = i * 256 + tid;
      int qq = s >> 4, gc = s & 15;
      *(float4*)&sRP[qq * 64 + ((gc ^ (qq & 15)) * 4)] = rg[i];
    }
  };

  const int NT = Ln / 64;  // 32
  // prologue: tile 0 staged + rp(0) written
  stage(0, 0);
  float4 rg[8];
  rpload(0, rg);
  rpwrite(rg);

  for (int kt = 0; kt < NT; ++kt) {
    const int cur = kt & 1;
    __syncthreads();  // bar1: publishes sRP(kt), drains staging(kt)
    if (kt + 1 < NT) {
      stage(cur ^ 1, kt + 1);
      rpload(kt + 1, rg);   // issue early; consumed after bar2 (T14)
    }

    // ---- S^T = K.Q^T : 2 k-blocks x 8 e-slices (A=K, B=Q) ----
    const u16* sKc = sK[cur];
    f32x16 S0 = (f32x16)0.0f, S1 = (f32x16)0.0f;
    __builtin_amdgcn_s_setprio(1);
#pragma unroll
    for (int es = 0; es < 8; ++es) {
      int gsw = ((es * 2 + hi) ^ (q5 & 15)) * 8;
      s16x8 ak0 = *(const s16x8*)&sKc[q5 * 128 + gsw];
      S0 = __builtin_amdgcn_mfma_f32_32x32x16_bf16(ak0, aq[es], S0, 0, 0, 0);
      s16x8 ak1 = *(const s16x8*)&sKc[(32 + q5) * 128 + gsw];
      S1 = __builtin_amdgcn_mfma_f32_32x32x16_bf16(ak1, aq[es], S1, 0, 0, 0);
    }
    __builtin_amdgcn_s_setprio(0);

    // ---- exp + pack to bf16 pairs (all in-register; q = q5 lane-local) ----
    // S reg i (per 32-k block): k = (i>>2)*8 + hi*4 + (i&3); rp quads align.
    uint32_t pkv[16];
#pragma unroll
    for (int kbi = 0; kbi < 2; ++kbi) {
      const f32x16 Sa = kbi ? S1 : S0;
#pragma unroll
      for (int g = 0; g < 4; ++g) {
        f32x4 rp4 = *(const f32x4*)&sRP[(w * 32 + q5) * 64 +
                                        (((kbi * 8 + g * 2 + hi) ^ (q5 & 15)) * 4)];
        float4 mv4 = *(const float4*)(mk + kt * 64 + kbi * 32 + g * 8 + hi * 4);
        float p0 = __expf(fmaf(gv, rp4[0], fmaf(Sa[4 * g + 0], 0.125f, mv4.x)));
        float p1 = __expf(fmaf(gv, rp4[1], fmaf(Sa[4 * g + 1], 0.125f, mv4.y)));
        float p2 = __expf(fmaf(gv, rp4[2], fmaf(Sa[4 * g + 2], 0.125f, mv4.z)));
        float p3 = __expf(fmaf(gv, rp4[3], fmaf(Sa[4 * g + 3], 0.125f, mv4.w)));
        l_part += (p0 + p1) + (p2 + p3);
        uint32_t c0, c1;
        asm("v_cvt_pk_bf16_f32 %0, %1, %2" : "=v"(c0) : "v"(p0), "v"(p1));
        asm("v_cvt_pk_bf16_f32 %0, %1, %2" : "=v"(c1) : "v"(p2), "v"(p3));
        pkv[kbi * 8 + g * 2] = c0;
        pkv[kbi * 8 + g * 2 + 1] = c1;
      }
    }
    // cross-half exchange: lane gets its 8 consecutive k per 16-k PV slice.
    // swap(X,Y): X' = {X_lo, Y_lo}, Y' = {X_hi, Y_hi}
#pragma unroll
    for (int base = 0; base < 16; base += 8) {
      asm volatile("v_permlane32_swap_b32 %0, %1" : "+v"(pkv[base + 0]), "+v"(pkv[base + 2]));
      asm volatile("v_permlane32_swap_b32 %0, %1" : "+v"(pkv[base + 1]), "+v"(pkv[base + 3]));
      asm volatile("v_permlane32_swap_b32 %0, %1" : "+v"(pkv[base + 4]), "+v"(pkv[base + 6]));
      asm volatile("v_permlane32_swap_b32 %0, %1" : "+v"(pkv[base + 5]), "+v"(pkv[base + 7]));
    }

    if (kt + 1 < NT) {
      // pin rel_pos regs live here: load issued early, waited after QK^T+exp cover
#pragma unroll
      for (int i = 0; i < 8; ++i)
        asm volatile("" : "+v"(rg[i].x), "+v"(rg[i].y), "+v"(rg[i].z), "+v"(rg[i].w));
    }
    __syncthreads();  // bar2: all waves done reading sRP(kt)
    if (kt + 1 < NT) rpwrite(rg);

    // ---- O += P.V : 4 k-slices x 2 hs-blocks (A=P from regs, B=V^T) ----
    const u16* sVc = sVt[cur];
    __builtin_amdgcn_s_setprio(1);
#pragma unroll
    for (int ks2 = 0; ks2 < 4; ++ks2) {
      union { uint32_t u[4]; s16x8 v; } pu;
      pu.u[0] = pkv[ks2 * 4 + 0];
      pu.u[1] = pkv[ks2 * 4 + 1];
      pu.u[2] = pkv[ks2 * 4 + 2];
      pu.u[3] = pkv[ks2 * 4 + 3];
      s16x8 pa = pu.v;
      int gsw = ((ks2 * 2 + hi) ^ (q5 & 7)) * 8;
      s16x8 bv0 = *(const s16x8*)&sVc[q5 * 64 + gsw];
      O0 = __builtin_amdgcn_mfma_f32_32x32x16_bf16(pa, bv0, O0, 0, 0, 0);
      s16x8 bv1 = *(const s16x8*)&sVc[(32 + q5) * 64 + gsw];
      O1 = __builtin_amdgcn_mfma_f32_32x32x16_bf16(pa, bv1, O1, 0, 0, 0);
    }
    __builtin_amdgcn_s_setprio(0);
  }

  // ---- epilogue: l = own + partner half; 1/l distributed via shuffle (no LDS) ----
  float lt = l_part + __shfl_xor(l_part, 32, 64);
  float inv = 1.0f / lt;
#pragma unroll
  for (int i = 0; i < 16; ++i) {
    int qr = (i & 3) + 8 * (i >> 2) + 4 * hi;  // O row within 32-q block
    float iv = __shfl(inv, qr, 64);            // lane qr holds row qr's 1/l
    int qg = q0 + w * 32 + qr;
    float* orow = out + ((size_t)b * Ln + qg) * HIDn + h * 64;
    orow[q5] = O0[i] * iv;
    orow[32 + q5] = O1[i] * iv;
  }
}

extern "C" void kernel_launch(void* const* d_in, const int* in_sizes, int n_in,
                              void* d_out, int out_size, void* d_ws, size_t ws_size,
                              hipStream_t stream) {
  const float* hs = (const float*)d_in[0];
  const float* mask = (const float*)d_in[1];
  const float* relpos = (const float*)d_in[2];
  const float* Wq = (const float*)d_in[3];
  const float* bq = (const float*)d_in[4];
  const float* Wk = (const float*)d_in[5];
  const float* Wv = (const float*)d_in[6];
  const float* bv = (const float*)d_in[7];
  const float* Wg = (const float*)d_in[8];
  const float* bg = (const float*)d_in[9];
  const float* eco = (const float*)d_in[10];
  float* out = (float*)d_out;

  char* ws = (char*)d_ws;
  u16* hsb = (u16*)ws;                           // 8MB
  u16* wb = (u16*)(ws + (8ull << 20));           // 10MB
  u16* qb = (u16*)(ws + (18ull << 20));          // 16MB
  u16* kb = (u16*)(ws + (34ull << 20));          // 16MB
  u16* vt = (u16*)(ws + (50ull << 20));          // 8MB
  float* gate = (float*)(ws + (58ull << 20));    // 256KB
  float* wgu = (float*)(ws + (58ull << 20) + (1ull << 19));
  float* wgr = wgu + 128;

  castbf<<<4096, 256, 0, stream>>>(hs, hsb, 4096 * 1024);
  castbf<<<2048, 256, 0, stream>>>(Wq, wb, 2048 * 1024);
  castbf<<<2048, 256, 0, stream>>>(Wk, wb + 2048 * 1024, 2048 * 1024);
  castbf<<<1024, 256, 0, stream>>>(Wv, wb + 4096 * 1024, 1024 * 1024);
  wgprep<<<1, 128, 0, stream>>>(Wg, wgu, wgr);
  qkv_gemm<<<dim3(40, 32), 256, 0, stream>>>(hsb, wb, bq, bv, qb, kb, vt);
  gate_kernel<<<256, 256, 0, stream>>>(qb, wgu, wgr, bg, eco, gate);
  attn_kernel<<<dim3(32, 16), 256, 0, stream>>>(qb, kb, vt, mask, relpos, gate, out);
}